// Round 3
// baseline (4047.216 us; speedup 1.0000x reference)
//
#include <hip/hip_runtime.h>
#include <hip/hip_bf16.h>
#include <math.h>

#define N_NODES 50000
#define E_EDGES 800000
#define S_DIM 128
#define V_DIM 16
#define HM 17            // message GVP dim_h / vectors-in
#define KM 161           // 128 + 16 rbf + 17 sh
#define HU 32            // update GVP vectors-in
#define KU 288           // 256 + 32 sh

#define EB 64            // edges per block
#define LDA 164          // A-tile leading dim (161 used)
#define NB 32            // nodes per block
#define LDA2 292         // node A-tile leading dim (288 used)

__device__ __forceinline__ float bf2f(unsigned short u) {
    union { unsigned int i; float f; } w; w.i = ((unsigned int)u) << 16; return w.f;
}
__device__ __forceinline__ unsigned short f2bf(float f) {
    union { float f; unsigned int i; } w; w.f = f;
    unsigned int x = w.i;
    x += 0x7fff + ((x >> 16) & 1);   // round-to-nearest-even
    return (unsigned short)(x >> 16);
}
__device__ __forceinline__ float silu_f(float x) { return x / (1.f + __expf(-x)); }
__device__ __forceinline__ float sigm_f(float x) { return 1.f / (1.f + __expf(-x)); }
// scalar dual-dtype load; branch (not ternary) so neither load is speculated OOB
__device__ __forceinline__ float ldf(const void* p, int i, int m) {
    if (m) return ((const float*)p)[i];
    return bf2f(((const unsigned short*)p)[i]);
}

// ---------------------------------------------------------------------------
// Detector: decide whether float inputs are fp32 (flag=1) or bf16 (flag=0).
// For fp32 data, even ushort indices are float mantissa low-halves -> as bf16
// their exponent field is ~uniform; exponent >140 (|x|>2^13) occurs ~45% of
// the time. For genuine bf16 N(0,1) data it never occurs.
// ---------------------------------------------------------------------------
__global__ void detect_kernel(const unsigned short* __restrict__ s_us,
                              int* __restrict__ flag) {
    int t = threadIdx.x;
    int huge = 0;
    for (int k = 0; k < 16; ++k) {
        unsigned short u = s_us[2 * (t + 64 * k)];
        int e = (u >> 7) & 0xFF;
        if (e > 140) huge = 1;
    }
    if (huge) atomicOr(flag, 1);
}

// ---------------------------------------------------------------------------
// Edge (message) kernel: per block, 64 edges.
// ---------------------------------------------------------------------------
__global__ __launch_bounds__(256) void edge_kernel(
    const void* sP, const void* vP, const void* xP,
    const void* WhP, const void* WuP, const void* WfP,
    const void* bfP, const void* WgP, const void* bgP,
    const int* __restrict__ ei,
    const int* __restrict__ flagp,
    float* __restrict__ agg_s,               // [N][128]
    float* __restrict__ agg_v)               // [N][48]
{
    __shared__ float A[EB * LDA];        // 41984 B
    __shared__ float Bs[4096];           // 16384 B: vin [64][52] (0..3326) | Wu stash 3328..3599 | Wf chunks | Wg stash 0..2047
    __shared__ float WhWu[HM * 16];      // 1088 B
    __shared__ float gates[EB * 16];     // 4096 B (Wh stash 0..288 early)
    __shared__ int srcb[EB], dstb[EB];   // 512 B

    const int t = threadIdx.x;
    const int e0 = blockIdx.x * EB;
    const int m = flagp[0];              // 1 = fp32 inputs

    // phase 0a: indices + stage Wh -> gates[0..288], Wu -> Bs[3328..3599]
    if (t < EB) {
        srcb[t] = ei[e0 + t];
        dstb[t] = ei[E_EDGES + e0 + t];
    }
    if (m) {
        const float* Wh = (const float*)WhP;
        const float* Wu = (const float*)WuP;
        for (int i = t; i < HM * HM; i += 256) gates[i] = Wh[i];
        for (int i = t; i < HM * 16; i += 256) Bs[3328 + i] = Wu[i];
    } else {
        const unsigned short* Wh = (const unsigned short*)WhP;
        const unsigned short* Wu = (const unsigned short*)WuP;
        for (int i = t; i < HM * HM; i += 256) gates[i] = bf2f(Wh[i]);
        for (int i = t; i < HM * 16; i += 256) Bs[3328 + i] = bf2f(Wu[i]);
    }
    __syncthreads();

    // phase 0b: WhWu = Wh @ Wu  [17][16] (from LDS stashes)
    for (int idx = t; idx < HM * 16; idx += 256) {
        int vv = idx / 16, o = idx % 16;
        float acc = 0.f;
        for (int h = 0; h < HM; ++h)
            acc += gates[vv * HM + h] * Bs[3328 + h * 16 + o];
        WhWu[idx] = acc;
    }
    // phase 1a: gather s[src] rows into A cols 0..127
    {
        int tj = t & 31, te = t >> 5;
        if (m) {
            const float* sF = (const float*)sP;
            for (int r = 0; r < 8; ++r) {
                int e = te + 8 * r;
                float4 u = *(const float4*)(sF + (size_t)srcb[e] * S_DIM + tj * 4);
                float* a = &A[e * LDA + tj * 4];
                a[0] = u.x; a[1] = u.y; a[2] = u.z; a[3] = u.w;
            }
        } else {
            const unsigned short* sU = (const unsigned short*)sP;
            for (int r = 0; r < 8; ++r) {
                int e = te + 8 * r;
                ushort4 u = *(const ushort4*)(sU + (size_t)srcb[e] * S_DIM + tj * 4);
                float* a = &A[e * LDA + tj * 4];
                a[0] = bf2f(u.x); a[1] = bf2f(u.y); a[2] = bf2f(u.z); a[3] = bf2f(u.w);
            }
        }
    }
    // phase 1b: vin staging into Bs[e][52] (48 = v[src], 48..50 = unit) + geometry/rbf
    {
        int e = t >> 2, q = t & 3;
        int src = srcb[e];
        float* vin = &Bs[e * 52 + q * 12];
        if (m) {
            const float* vp = (const float*)vP + (size_t)src * 48 + q * 12;
            for (int i = 0; i < 3; ++i) {
                float4 u = *(const float4*)(vp + i * 4);
                vin[i * 4 + 0] = u.x; vin[i * 4 + 1] = u.y;
                vin[i * 4 + 2] = u.z; vin[i * 4 + 3] = u.w;
            }
        } else {
            const unsigned short* vp = (const unsigned short*)vP + (size_t)src * 48 + q * 12;
            for (int i = 0; i < 3; ++i) {
                ushort4 u = *(const ushort4*)(vp + i * 4);
                vin[i * 4 + 0] = bf2f(u.x); vin[i * 4 + 1] = bf2f(u.y);
                vin[i * 4 + 2] = bf2f(u.z); vin[i * 4 + 3] = bf2f(u.w);
            }
        }
        if (q == 0) {
            int dst = dstb[e];
            float dxc[3]; float d2 = 0.f;
            for (int c = 0; c < 3; ++c) {
                float xs = ldf(xP, src * 3 + c, m);
                float xd = ldf(xP, dst * 3 + c, m);
                dxc[c] = xd - xs; d2 += dxc[c] * dxc[c];
            }
            float dist = sqrtf(fmaxf(d2, 1e-8f));
            float inv = 1.f / dist;
            for (int c = 0; c < 3; ++c) Bs[e * 52 + 48 + c] = dxc[c] * inv;
            for (int k = 0; k < 16; ++k) {
                float mu = (20.f / 15.f) * (float)k;
                float z = (dist - mu) * (1.f / 1.25f);
                A[e * LDA + 128 + k] = __expf(-z * z);
            }
        }
    }
    __syncthreads();

    // phase 1c: sh[e][h] = || sum_v vin[v]*Wh[v,h] ||  -> A cols 144..160 (Wh from gates stash)
    for (int idx = t; idx < EB * HM; idx += 256) {
        int e = idx / HM, h = idx % HM;
        const float* vin = &Bs[e * 52];
        float vh0 = 0.f, vh1 = 0.f, vh2 = 0.f;
        for (int vv = 0; vv < HM; ++vv) {
            float w = gates[vv * HM + h];
            vh0 += vin[vv * 3 + 0] * w;
            vh1 += vin[vv * 3 + 1] * w;
            vh2 += vin[vv * 3 + 2] * w;
        }
        A[e * LDA + 144 + h] = sqrtf(fmaxf(vh0 * vh0 + vh1 * vh1 + vh2 * vh2, 1e-8f));
    }
    // phase 1d: Vu[e][o][c] into registers (12 per thread, flat 64*48)
    float vureg[12];
    for (int r = 0; r < 12; ++r) {
        int idx = t + 256 * r;
        int e = idx / 48, oc = idx % 48, o = oc / 3, c = oc % 3;
        const float* vin = &Bs[e * 52];
        float acc = 0.f;
        for (int vv = 0; vv < HM; ++vv)
            acc += vin[vv * 3 + c] * WhWu[vv * 16 + o];
        vureg[r] = acc;
    }
    __syncthreads();   // Bs free; A complete

    // phase 2: GEMM feats[64][128] = A[64][161] @ Wf[161][128]
    const int tj = t & 15, te = t >> 4;
    const int j0 = tj * 8, eb = te * 4;
    float acc[4][8];
    #pragma unroll
    for (int i = 0; i < 4; ++i)
        #pragma unroll
        for (int j = 0; j < 8; ++j) acc[i][j] = 0.f;

    for (int kk = 0; kk < KM; kk += 32) {
        int kmax = min(32, KM - kk);
        if (m) {
            const float* WfF = (const float*)WfP;
            for (int idx = t; idx < kmax * 32; idx += 256) {
                int kt = idx >> 5, col4 = (idx & 31) * 4;
                float4 u = *(const float4*)(WfF + (size_t)(kk + kt) * 128 + col4);
                float* b = &Bs[kt * 128 + col4];
                b[0] = u.x; b[1] = u.y; b[2] = u.z; b[3] = u.w;
            }
        } else {
            const unsigned short* WfU = (const unsigned short*)WfP;
            for (int idx = t; idx < kmax * 32; idx += 256) {
                int kt = idx >> 5, col4 = (idx & 31) * 4;
                ushort4 u = *(const ushort4*)(WfU + (size_t)(kk + kt) * 128 + col4);
                float* b = &Bs[kt * 128 + col4];
                b[0] = bf2f(u.x); b[1] = bf2f(u.y); b[2] = bf2f(u.z); b[3] = bf2f(u.w);
            }
        }
        __syncthreads();
        for (int kt = 0; kt < kmax; ++kt) {
            float a0 = A[(eb + 0) * LDA + kk + kt];
            float a1 = A[(eb + 1) * LDA + kk + kt];
            float a2 = A[(eb + 2) * LDA + kk + kt];
            float a3 = A[(eb + 3) * LDA + kk + kt];
            const float* brow = &Bs[kt * 128 + j0];
            #pragma unroll
            for (int j = 0; j < 8; ++j) {
                float b = brow[j];
                acc[0][j] += a0 * b; acc[1][j] += a1 * b;
                acc[2][j] += a2 * b; acc[3][j] += a3 * b;
            }
        }
        __syncthreads();
    }
    // bias + silu; scatter ms; store feats into A cols 0..127
    float breg[8];
    #pragma unroll
    for (int j = 0; j < 8; ++j) breg[j] = ldf(bfP, j0 + j, m);
    #pragma unroll
    for (int i = 0; i < 4; ++i) {
        int e = eb + i;
        float* aout = &A[e * LDA + j0];
        float* gp = &agg_s[(size_t)dstb[e] * S_DIM + j0];
        #pragma unroll
        for (int j = 0; j < 8; ++j) {
            float xv = acc[i][j] + breg[j];
            float f = silu_f(xv);
            aout[j] = f;
            atomicAdd(&gp[j], f);
        }
    }
    __syncthreads();
    // stage Wg [128][16] -> Bs[0..2047]
    if (m) {
        const float* Wg = (const float*)WgP;
        for (int i = t; i < 2048; i += 256) Bs[i] = Wg[i];
    } else {
        const unsigned short* Wg = (const unsigned short*)WgP;
        for (int i = t; i < 2048; i += 256) Bs[i] = bf2f(Wg[i]);
    }
    __syncthreads();
    // phase 3: gates[e][o] = sigmoid(feats @ Wg + bg)
    for (int r = 0; r < 4; ++r) {
        int idx = t + 256 * r;
        int e = idx / 16, o = idx % 16;
        const float* fe = &A[e * LDA];
        float g = ldf(bgP, o, m);
        for (int j = 0; j < S_DIM; ++j)
            g += fe[j] * Bs[j * 16 + o];
        gates[idx] = sigm_f(g);
    }
    __syncthreads();
    // phase 4: mv scatter
    for (int r = 0; r < 12; ++r) {
        int idx = t + 256 * r;
        int e = idx / 48, oc = idx % 48, o = oc / 3;
        float mvv = vureg[r] * gates[e * 16 + o];
        atomicAdd(&agg_v[(size_t)dstb[e] * 48 + oc], mvv);
    }
}

// ---------------------------------------------------------------------------
// Node (update) kernel: per block, 32 nodes. Update GVP + residual + LN.
// ---------------------------------------------------------------------------
__global__ __launch_bounds__(256) void node_kernel(
    const void* sP, const void* vP,
    const void* WhP, const void* WuP, const void* WfP,
    const void* bfP, const void* WgP, const void* bgP,
    const void* lngP, const void* lnbP,
    const int* __restrict__ flagp,
    const float* __restrict__ agg_s,         // [N][128]
    const float* __restrict__ agg_v,         // [N][48]
    void* outP)                              // [N*128] then [N*48]
{
    __shared__ float A2[NB * LDA2];      // 37376 B : 0..127 s, 128..255 agg_s/10 -> feats, 256..287 sh
    __shared__ float Bs2[4096];          // 16384 B : vcat [32][100] -> Wf chunks -> Wg stash -> v_res
    __shared__ float WhWu2[HU * 16];     // 2048 B
    __shared__ float gates2[NB * 16];    // 2048 B (Wu stash early)
    __shared__ float WhS[HU * HU];       // 4096 B
    __shared__ float mu_s[NB], rstd_s[NB], vn_s[NB];

    const int t = threadIdx.x;
    const int n0 = blockIdx.x * NB;
    const int m = flagp[0];

    // phase A: stage weights + s_cat + vcat
    if (m) {
        const float* Wh = (const float*)WhP;
        const float* Wu = (const float*)WuP;
        for (int i = t; i < HU * HU; i += 256) WhS[i] = Wh[i];
        for (int i = t; i < HU * 16; i += 256) gates2[i] = Wu[i];
    } else {
        const unsigned short* Wh = (const unsigned short*)WhP;
        const unsigned short* Wu = (const unsigned short*)WuP;
        for (int i = t; i < HU * HU; i += 256) WhS[i] = bf2f(Wh[i]);
        for (int i = t; i < HU * 16; i += 256) gates2[i] = bf2f(Wu[i]);
    }
    if (m) {
        const float* sF = (const float*)sP;
        for (int idx = t; idx < NB * 32; idx += 256) {
            int ni = idx >> 5, col4 = (idx & 31) * 4;
            int n = n0 + ni;
            float* a = &A2[ni * LDA2 + col4];
            if (n < N_NODES) {
                float4 u = *(const float4*)(sF + (size_t)n * 128 + col4);
                a[0] = u.x; a[1] = u.y; a[2] = u.z; a[3] = u.w;
            } else { a[0] = a[1] = a[2] = a[3] = 0.f; }
        }
    } else {
        const unsigned short* sU = (const unsigned short*)sP;
        for (int idx = t; idx < NB * 32; idx += 256) {
            int ni = idx >> 5, col4 = (idx & 31) * 4;
            int n = n0 + ni;
            float* a = &A2[ni * LDA2 + col4];
            if (n < N_NODES) {
                ushort4 u = *(const ushort4*)(sU + (size_t)n * 128 + col4);
                a[0] = bf2f(u.x); a[1] = bf2f(u.y); a[2] = bf2f(u.z); a[3] = bf2f(u.w);
            } else { a[0] = a[1] = a[2] = a[3] = 0.f; }
        }
    }
    for (int idx = t; idx < NB * 32; idx += 256) {       // agg part, float4 (always fp32 ws)
        int ni = idx >> 5, col4 = (idx & 31) * 4;
        int n = n0 + ni;
        float* a = &A2[ni * LDA2 + 128 + col4];
        if (n < N_NODES) {
            float4 u = *(const float4*)(agg_s + (size_t)n * 128 + col4);
            a[0] = u.x * 0.1f; a[1] = u.y * 0.1f; a[2] = u.z * 0.1f; a[3] = u.w * 0.1f;
        } else { a[0] = a[1] = a[2] = a[3] = 0.f; }
    }
    for (int idx = t; idx < NB * 96; idx += 256) {       // vcat = [v | agg_v/10]
        int ni = idx / 96, vc = idx % 96;
        int n = n0 + ni;
        float val = 0.f;
        if (n < N_NODES)
            val = (vc < 48) ? ldf(vP, n * 48 + vc, m)
                            : agg_v[(size_t)n * 48 + (vc - 48)] * 0.1f;
        Bs2[ni * 100 + vc] = val;
    }
    __syncthreads();
    // phase B: WhWu2 = Wh_u @ Wu_u ; sh_u -> A2 cols 256..287
    for (int idx = t; idx < HU * 16; idx += 256) {
        int vv = idx / 16, o = idx % 16;
        float acc = 0.f;
        for (int h = 0; h < HU; ++h)
            acc += WhS[vv * HU + h] * gates2[h * 16 + o];
        WhWu2[idx] = acc;
    }
    for (int idx = t; idx < NB * HU; idx += 256) {
        int ni = idx / HU, h = idx % HU;
        const float* vc = &Bs2[ni * 100];
        float vh0 = 0.f, vh1 = 0.f, vh2 = 0.f;
        for (int vv = 0; vv < HU; ++vv) {
            float w = WhS[vv * HU + h];
            vh0 += vc[vv * 3 + 0] * w; vh1 += vc[vv * 3 + 1] * w; vh2 += vc[vv * 3 + 2] * w;
        }
        A2[ni * LDA2 + 256 + h] = sqrtf(fmaxf(vh0 * vh0 + vh1 * vh1 + vh2 * vh2, 1e-8f));
    }
    __syncthreads();
    // phase C: Vu_u into registers (6 per thread, flat 32*48)
    float vureg[6];
    for (int r = 0; r < 6; ++r) {
        int idx = t + 256 * r;
        int ni = idx / 48, oc = idx % 48, o = oc / 3, c = oc % 3;
        const float* vc = &Bs2[ni * 100];
        float acc = 0.f;
        for (int vv = 0; vv < HU; ++vv)
            acc += vc[vv * 3 + c] * WhWu2[vv * 16 + o];
        vureg[r] = acc;
    }
    __syncthreads();

    // GEMM feats[32][128] = A2[32][288] @ Wf[288][128]
    const int tj = t & 15, tn = t >> 4;
    const int j0 = tj * 8, nb = tn * 2;
    float acc[2][8];
    #pragma unroll
    for (int i = 0; i < 2; ++i)
        #pragma unroll
        for (int j = 0; j < 8; ++j) acc[i][j] = 0.f;

    for (int kk = 0; kk < KU; kk += 32) {
        if (m) {
            const float* WfF = (const float*)WfP;
            for (int idx = t; idx < 32 * 32; idx += 256) {
                int kt = idx >> 5, col4 = (idx & 31) * 4;
                float4 u = *(const float4*)(WfF + (size_t)(kk + kt) * 128 + col4);
                float* b = &Bs2[kt * 128 + col4];
                b[0] = u.x; b[1] = u.y; b[2] = u.z; b[3] = u.w;
            }
        } else {
            const unsigned short* WfU = (const unsigned short*)WfP;
            for (int idx = t; idx < 32 * 32; idx += 256) {
                int kt = idx >> 5, col4 = (idx & 31) * 4;
                ushort4 u = *(const ushort4*)(WfU + (size_t)(kk + kt) * 128 + col4);
                float* b = &Bs2[kt * 128 + col4];
                b[0] = bf2f(u.x); b[1] = bf2f(u.y); b[2] = bf2f(u.z); b[3] = bf2f(u.w);
            }
        }
        __syncthreads();
        for (int kt = 0; kt < 32; ++kt) {
            float a0 = A2[(nb + 0) * LDA2 + kk + kt];
            float a1 = A2[(nb + 1) * LDA2 + kk + kt];
            const float* brow = &Bs2[kt * 128 + j0];
            #pragma unroll
            for (int j = 0; j < 8; ++j) {
                float b = brow[j];
                acc[0][j] += a0 * b; acc[1][j] += a1 * b;
            }
        }
        __syncthreads();
    }
    // bias + silu -> feats into A2 cols 128..255
    float breg[8];
    #pragma unroll
    for (int j = 0; j < 8; ++j) breg[j] = ldf(bfP, j0 + j, m);
    #pragma unroll
    for (int i = 0; i < 2; ++i) {
        float* aout = &A2[(nb + i) * LDA2 + 128 + j0];
        #pragma unroll
        for (int j = 0; j < 8; ++j) {
            float xv = acc[i][j] + breg[j];
            aout[j] = silu_f(xv);
        }
    }
    __syncthreads();
    // stage Wg -> Bs2[0..2047]
    if (m) {
        const float* Wg = (const float*)WgP;
        for (int i = t; i < 2048; i += 256) Bs2[i] = Wg[i];
    } else {
        const unsigned short* Wg = (const unsigned short*)WgP;
        for (int i = t; i < 2048; i += 256) Bs2[i] = bf2f(Wg[i]);
    }
    __syncthreads();
    // gates
    for (int r = 0; r < 2; ++r) {
        int idx = t + 256 * r;
        int ni = idx / 16, o = idx % 16;
        const float* fe = &A2[ni * LDA2 + 128];
        float g = ldf(bgP, o, m);
        for (int j = 0; j < 128; ++j)
            g += fe[j] * Bs2[j * 16 + o];
        gates2[idx] = sigm_f(g);
    }
    __syncthreads();
    // v_res = v + gate*Vu  -> Bs2[ni*48+oc]
    for (int r = 0; r < 6; ++r) {
        int idx = t + 256 * r;
        int ni = idx / 48, oc = idx % 48, o = oc / 3;
        int n = n0 + ni;
        float vres = 0.f;
        if (n < N_NODES)
            vres = ldf(vP, n * 48 + oc, m) + vureg[r] * gates2[ni * 16 + o];
        Bs2[ni * 48 + oc] = vres;
    }
    __syncthreads();
    // per-node stats
    if (t < NB) {
        const float* arow = &A2[t * LDA2];
        float sum = 0.f, sumsq = 0.f;
        for (int j = 0; j < 128; ++j) {
            float xr = arow[j] + arow[128 + j];
            sum += xr; sumsq += xr * xr;
        }
        float mu = sum * (1.f / 128.f);
        float var = sumsq * (1.f / 128.f) - mu * mu;
        mu_s[t] = mu;
        rstd_s[t] = rsqrtf(fmaxf(var, 0.f) + 1e-5f);
        const float* vr = &Bs2[t * 48];
        float accv = 0.f;
        for (int o = 0; o < 16; ++o) {
            float mm = vr[o*3]*vr[o*3] + vr[o*3+1]*vr[o*3+1] + vr[o*3+2]*vr[o*3+2];
            accv += fmaxf(mm, 1e-8f);
        }
        vn_s[t] = sqrtf(accv * (1.f / 16.f) + 1e-5f) + 1e-5f;
    }
    __syncthreads();
    // outputs (dtype per mode)
    float* outF = (float*)outP;
    unsigned short* outU = (unsigned short*)outP;
    for (int idx = t; idx < NB * 128; idx += 256) {
        int ni = idx >> 7, j = idx & 127;
        int n = n0 + ni;
        if (n < N_NODES) {
            float xr = A2[ni * LDA2 + j] + A2[ni * LDA2 + 128 + j];
            float o = (xr - mu_s[ni]) * rstd_s[ni] * ldf(lngP, j, m) + ldf(lnbP, j, m);
            if (m) outF[(size_t)n * 128 + j] = o;
            else   outU[(size_t)n * 128 + j] = f2bf(o);
        }
    }
    for (int idx = t; idx < NB * 48; idx += 256) {
        int ni = idx / 48, oc = idx % 48;
        int n = n0 + ni;
        if (n < N_NODES) {
            float o = Bs2[ni * 48 + oc] / vn_s[ni];
            if (m) outF[(size_t)N_NODES * 128 + (size_t)n * 48 + oc] = o;
            else   outU[(size_t)N_NODES * 128 + (size_t)n * 48 + oc] = f2bf(o);
        }
    }
}

extern "C" void kernel_launch(void* const* d_in, const int* in_sizes, int n_in,
                              void* d_out, int out_size, void* d_ws, size_t ws_size,
                              hipStream_t stream) {
    const int* ei = (const int*)d_in[17];

    int* flag = (int*)d_ws;
    float* agg_s = (float*)((char*)d_ws + 64);
    float* agg_v = agg_s + (size_t)N_NODES * 128;
    hipMemsetAsync(d_ws, 0, 64 + (size_t)N_NODES * (128 + 48) * sizeof(float), stream);

    detect_kernel<<<1, 64, 0, stream>>>((const unsigned short*)d_in[0], flag);

    edge_kernel<<<E_EDGES / EB, 256, 0, stream>>>(
        d_in[0], d_in[1], d_in[2], d_in[3], d_in[4], d_in[5],
        d_in[6], d_in[7], d_in[8], ei, flag, agg_s, agg_v);
    node_kernel<<<(N_NODES + NB - 1) / NB, 256, 0, stream>>>(
        d_in[0], d_in[1], d_in[9], d_in[10], d_in[11], d_in[12],
        d_in[13], d_in[14], d_in[15], d_in[16], flag,
        agg_s, agg_v, d_out);
}

// Round 4
// 2400.835 us; speedup vs baseline: 1.6858x; 1.6858x over previous
//
#include <hip/hip_runtime.h>
#include <hip/hip_bf16.h>
#include <math.h>

#define N_NODES 50000
#define E_EDGES 800000
#define S_DIM 128
#define V_DIM 16
#define HM 17            // message GVP dim_h / vectors-in
#define KM 161           // 128 + 16 rbf + 17 sh
#define HU 32            // update GVP vectors-in
#define KU 288           // 256 + 32 sh

#define EB 32            // edges per block (32: LDS 32.6KB -> 4 blocks/CU)
#define LDA 164          // A-tile leading dim (161 used)
#define NB 32            // nodes per block
#define LDA2 292         // node A-tile leading dim (288 used)

__device__ __forceinline__ float bf2f(unsigned short u) {
    union { unsigned int i; float f; } w; w.i = ((unsigned int)u) << 16; return w.f;
}
__device__ __forceinline__ unsigned short f2bf(float f) {
    union { float f; unsigned int i; } w; w.f = f;
    unsigned int x = w.i;
    x += 0x7fff + ((x >> 16) & 1);   // round-to-nearest-even
    return (unsigned short)(x >> 16);
}
__device__ __forceinline__ float silu_f(float x) { return x / (1.f + __expf(-x)); }
__device__ __forceinline__ float sigm_f(float x) { return 1.f / (1.f + __expf(-x)); }
// scalar dual-dtype load; branch (not ternary) so neither load is speculated OOB
__device__ __forceinline__ float ldf(const void* p, int i, int m) {
    if (m) return ((const float*)p)[i];
    return bf2f(((const unsigned short*)p)[i]);
}

// ---------------------------------------------------------------------------
// Detector: fp32 (flag=1) vs bf16 (flag=0) float inputs. For fp32 data the
// even ushorts are float mantissa low-halves -> bf16-decoded exponents are
// ~uniform; exponent >140 occurs ~45% per sample. Genuine N(0,1) bf16: never.
// ---------------------------------------------------------------------------
__global__ void detect_kernel(const unsigned short* __restrict__ s_us,
                              int* __restrict__ flag) {
    int t = threadIdx.x;
    int huge = 0;
    for (int k = 0; k < 16; ++k) {
        unsigned short u = s_us[2 * (t + 64 * k)];
        int e = (u >> 7) & 0xFF;
        if (e > 140) huge = 1;
    }
    if (huge) atomicOr(flag, 1);
}

// ---------------------------------------------------------------------------
// Edge (message) kernel: per block, 32 edges. Column mapping tj+16*jj so
// atomic scatters are lane-contiguous (full 64B lines) and LDS B-reads are
// broadcast-clean. 4 blocks/CU (LDS 32.6KB, VGPR<=128).
// ---------------------------------------------------------------------------
__global__ __launch_bounds__(256, 4) void edge_kernel(
    const void* sP, const void* vP, const void* xP,
    const void* WhP, const void* WuP, const void* WfP,
    const void* bfP, const void* WgP, const void* bgP,
    const int* __restrict__ ei,
    const int* __restrict__ flagp,
    float* __restrict__ agg_s,               // [N][128]
    float* __restrict__ agg_v)               // [N][48]
{
    __shared__ float A[EB * LDA];        // 20992 B: 0..127 s->feats, 128..143 rbf, 144..160 sh
    __shared__ float Bs[2048];           // 8192 B: vin [32][52] + Wu@1664 | Wf 16-row chunks | Wg stash
    __shared__ float WhWu[HM * 16];      // 1088 B
    __shared__ float gates[EB * 16];     // 2048 B (Wh stash 0..288 early)
    __shared__ int srcb[EB], dstb[EB];   // 256 B

    const int t = threadIdx.x;
    const int e0 = blockIdx.x * EB;
    const int m = flagp[0];              // 1 = fp32 inputs

    // phase 0a: indices + stage Wh -> gates[0..288], Wu -> Bs[1664..1935]
    if (t < EB) {
        srcb[t] = ei[e0 + t];
        dstb[t] = ei[E_EDGES + e0 + t];
    }
    if (m) {
        const float* Wh = (const float*)WhP;
        const float* Wu = (const float*)WuP;
        for (int i = t; i < HM * HM; i += 256) gates[i] = Wh[i];
        for (int i = t; i < HM * 16; i += 256) Bs[1664 + i] = Wu[i];
    } else {
        const unsigned short* Wh = (const unsigned short*)WhP;
        const unsigned short* Wu = (const unsigned short*)WuP;
        for (int i = t; i < HM * HM; i += 256) gates[i] = bf2f(Wh[i]);
        for (int i = t; i < HM * 16; i += 256) Bs[1664 + i] = bf2f(Wu[i]);
    }
    __syncthreads();

    // phase 0b: WhWu = Wh @ Wu  [17][16] (from LDS stashes)
    for (int idx = t; idx < HM * 16; idx += 256) {
        int vv = idx / 16, o = idx % 16;
        float acc = 0.f;
        for (int h = 0; h < HM; ++h)
            acc += gates[vv * HM + h] * Bs[1664 + h * 16 + o];
        WhWu[idx] = acc;
    }
    // phase 1a: gather s[src] rows into A cols 0..127 (32 edges x 32 col4-groups)
    {
        int tj = t & 31, te = t >> 5;     // te 0..7
        if (m) {
            const float* sF = (const float*)sP;
            for (int r = 0; r < 4; ++r) {
                int e = te + 8 * r;
                float4 u = *(const float4*)(sF + (size_t)srcb[e] * S_DIM + tj * 4);
                float* a = &A[e * LDA + tj * 4];
                a[0] = u.x; a[1] = u.y; a[2] = u.z; a[3] = u.w;
            }
        } else {
            const unsigned short* sU = (const unsigned short*)sP;
            for (int r = 0; r < 4; ++r) {
                int e = te + 8 * r;
                ushort4 u = *(const ushort4*)(sU + (size_t)srcb[e] * S_DIM + tj * 4);
                float* a = &A[e * LDA + tj * 4];
                a[0] = bf2f(u.x); a[1] = bf2f(u.y); a[2] = bf2f(u.z); a[3] = bf2f(u.w);
            }
        }
    }
    // phase 1b: vin into Bs[e][52] (48 = v[src], 48..50 = unit) + geometry/rbf
    if (t < 128) {
        int e = t >> 2, q = t & 3;
        int src = srcb[e];
        float* vin = &Bs[e * 52 + q * 12];
        if (m) {
            const float* vp = (const float*)vP + (size_t)src * 48 + q * 12;
            for (int i = 0; i < 3; ++i) {
                float4 u = *(const float4*)(vp + i * 4);
                vin[i * 4 + 0] = u.x; vin[i * 4 + 1] = u.y;
                vin[i * 4 + 2] = u.z; vin[i * 4 + 3] = u.w;
            }
        } else {
            const unsigned short* vp = (const unsigned short*)vP + (size_t)src * 48 + q * 12;
            for (int i = 0; i < 3; ++i) {
                ushort4 u = *(const ushort4*)(vp + i * 4);
                vin[i * 4 + 0] = bf2f(u.x); vin[i * 4 + 1] = bf2f(u.y);
                vin[i * 4 + 2] = bf2f(u.z); vin[i * 4 + 3] = bf2f(u.w);
            }
        }
        if (q == 0) {
            int dst = dstb[e];
            float dxc[3]; float d2 = 0.f;
            for (int c = 0; c < 3; ++c) {
                float xs = ldf(xP, src * 3 + c, m);
                float xd = ldf(xP, dst * 3 + c, m);
                dxc[c] = xd - xs; d2 += dxc[c] * dxc[c];
            }
            float dist = sqrtf(fmaxf(d2, 1e-8f));
            float inv = 1.f / dist;
            for (int c = 0; c < 3; ++c) Bs[e * 52 + 48 + c] = dxc[c] * inv;
            for (int k = 0; k < 16; ++k) {
                float mu = (20.f / 15.f) * (float)k;
                float z = (dist - mu) * (1.f / 1.25f);
                A[e * LDA + 128 + k] = __expf(-z * z);
            }
        }
    }
    __syncthreads();

    // phase 1c: sh[e][h] = || sum_v vin[v]*Wh[v,h] ||  -> A cols 144..160
    for (int idx = t; idx < EB * HM; idx += 256) {
        int e = idx / HM, h = idx % HM;
        const float* vin = &Bs[e * 52];
        float vh0 = 0.f, vh1 = 0.f, vh2 = 0.f;
        for (int vv = 0; vv < HM; ++vv) {
            float w = gates[vv * HM + h];
            vh0 += vin[vv * 3 + 0] * w;
            vh1 += vin[vv * 3 + 1] * w;
            vh2 += vin[vv * 3 + 2] * w;
        }
        A[e * LDA + 144 + h] = sqrtf(fmaxf(vh0 * vh0 + vh1 * vh1 + vh2 * vh2, 1e-8f));
    }
    // phase 1d: Vu[e][o][c] into registers (6 per thread, flat 32*48)
    float vureg[6];
    for (int r = 0; r < 6; ++r) {
        int idx = t + 256 * r;
        int e = idx / 48, oc = idx % 48, o = oc / 3, c = oc % 3;
        const float* vin = &Bs[e * 52];
        float acc = 0.f;
        for (int vv = 0; vv < HM; ++vv)
            acc += vin[vv * 3 + c] * WhWu[vv * 16 + o];
        vureg[r] = acc;
    }
    __syncthreads();   // Bs free; A complete

    // phase 2: GEMM feats[32][128] = A[32][161] @ Wf[161][128]
    // thread (tj,te): edges eb=te*2 +{0,1}, cols {tj + 16*jj}
    const int tj = t & 15, te = t >> 4;
    const int eb = te * 2;
    float acc[2][8];
    #pragma unroll
    for (int i = 0; i < 2; ++i)
        #pragma unroll
        for (int j = 0; j < 8; ++j) acc[i][j] = 0.f;

    for (int kk = 0; kk < KM; kk += 16) {
        int kmax = min(16, KM - kk);
        if (m) {
            const float* WfF = (const float*)WfP;
            for (int idx = t; idx < kmax * 32; idx += 256) {
                int kt = idx >> 5, col4 = (idx & 31) * 4;
                float4 u = *(const float4*)(WfF + (size_t)(kk + kt) * 128 + col4);
                float* b = &Bs[kt * 128 + col4];
                b[0] = u.x; b[1] = u.y; b[2] = u.z; b[3] = u.w;
            }
        } else {
            const unsigned short* WfU = (const unsigned short*)WfP;
            for (int idx = t; idx < kmax * 32; idx += 256) {
                int kt = idx >> 5, col4 = (idx & 31) * 4;
                ushort4 u = *(const ushort4*)(WfU + (size_t)(kk + kt) * 128 + col4);
                float* b = &Bs[kt * 128 + col4];
                b[0] = bf2f(u.x); b[1] = bf2f(u.y); b[2] = bf2f(u.z); b[3] = bf2f(u.w);
            }
        }
        __syncthreads();
        for (int kt = 0; kt < kmax; ++kt) {
            float a0 = A[(eb + 0) * LDA + kk + kt];
            float a1 = A[(eb + 1) * LDA + kk + kt];
            const float* brow = &Bs[kt * 128 + tj];
            #pragma unroll
            for (int jj = 0; jj < 8; ++jj) {
                float b = brow[16 * jj];
                acc[0][jj] += a0 * b; acc[1][jj] += a1 * b;
            }
        }
        __syncthreads();
    }
    // bias + silu; scatter ms (lane-contiguous full-line atomics); feats -> A
    float breg[8];
    #pragma unroll
    for (int jj = 0; jj < 8; ++jj) breg[jj] = ldf(bfP, tj + 16 * jj, m);
    #pragma unroll
    for (int i = 0; i < 2; ++i) {
        int e = eb + i;
        float* aout = &A[e * LDA];
        float* gp = &agg_s[(size_t)dstb[e] * S_DIM];
        #pragma unroll
        for (int jj = 0; jj < 8; ++jj) {
            int col = tj + 16 * jj;
            float f = silu_f(acc[i][jj] + breg[jj]);
            aout[col] = f;
            atomicAdd(&gp[col], f);
        }
    }
    __syncthreads();
    // stage Wg [128][16] -> Bs[0..2047]
    if (m) {
        const float* Wg = (const float*)WgP;
        for (int i = t; i < 2048; i += 256) Bs[i] = Wg[i];
    } else {
        const unsigned short* Wg = (const unsigned short*)WgP;
        for (int i = t; i < 2048; i += 256) Bs[i] = bf2f(Wg[i]);
    }
    __syncthreads();
    // phase 3: gates[e][o] = sigmoid(feats @ Wg + bg)
    for (int r = 0; r < 2; ++r) {
        int idx = t + 256 * r;
        int e = idx / 16, o = idx % 16;
        const float* fe = &A[e * LDA];
        float g = ldf(bgP, o, m);
        for (int j = 0; j < S_DIM; ++j)
            g += fe[j] * Bs[j * 16 + o];
        gates[idx] = sigm_f(g);
    }
    __syncthreads();
    // phase 4: mv scatter (lane-contiguous)
    for (int r = 0; r < 6; ++r) {
        int idx = t + 256 * r;
        int e = idx / 48, oc = idx % 48, o = oc / 3;
        float mvv = vureg[r] * gates[e * 16 + o];
        atomicAdd(&agg_v[(size_t)dstb[e] * 48 + oc], mvv);
    }
}

// ---------------------------------------------------------------------------
// Node (update) kernel: per block, 32 nodes. Update GVP + residual + LN.
// ---------------------------------------------------------------------------
__global__ __launch_bounds__(256) void node_kernel(
    const void* sP, const void* vP,
    const void* WhP, const void* WuP, const void* WfP,
    const void* bfP, const void* WgP, const void* bgP,
    const void* lngP, const void* lnbP,
    const int* __restrict__ flagp,
    const float* __restrict__ agg_s,         // [N][128]
    const float* __restrict__ agg_v,         // [N][48]
    void* outP)                              // [N*128] then [N*48]
{
    __shared__ float A2[NB * LDA2];      // 37376 B : 0..127 s, 128..255 agg_s/10 -> feats, 256..287 sh
    __shared__ float Bs2[4096];          // 16384 B : vcat [32][100] -> Wf chunks -> Wg stash -> v_res
    __shared__ float WhWu2[HU * 16];     // 2048 B
    __shared__ float gates2[NB * 16];    // 2048 B (Wu stash early)
    __shared__ float WhS[HU * HU];       // 4096 B
    __shared__ float mu_s[NB], rstd_s[NB], vn_s[NB];

    const int t = threadIdx.x;
    const int n0 = blockIdx.x * NB;
    const int m = flagp[0];

    // phase A: stage weights + s_cat + vcat
    if (m) {
        const float* Wh = (const float*)WhP;
        const float* Wu = (const float*)WuP;
        for (int i = t; i < HU * HU; i += 256) WhS[i] = Wh[i];
        for (int i = t; i < HU * 16; i += 256) gates2[i] = Wu[i];
    } else {
        const unsigned short* Wh = (const unsigned short*)WhP;
        const unsigned short* Wu = (const unsigned short*)WuP;
        for (int i = t; i < HU * HU; i += 256) WhS[i] = bf2f(Wh[i]);
        for (int i = t; i < HU * 16; i += 256) gates2[i] = bf2f(Wu[i]);
    }
    if (m) {
        const float* sF = (const float*)sP;
        for (int idx = t; idx < NB * 32; idx += 256) {
            int ni = idx >> 5, col4 = (idx & 31) * 4;
            int n = n0 + ni;
            float* a = &A2[ni * LDA2 + col4];
            if (n < N_NODES) {
                float4 u = *(const float4*)(sF + (size_t)n * 128 + col4);
                a[0] = u.x; a[1] = u.y; a[2] = u.z; a[3] = u.w;
            } else { a[0] = a[1] = a[2] = a[3] = 0.f; }
        }
    } else {
        const unsigned short* sU = (const unsigned short*)sP;
        for (int idx = t; idx < NB * 32; idx += 256) {
            int ni = idx >> 5, col4 = (idx & 31) * 4;
            int n = n0 + ni;
            float* a = &A2[ni * LDA2 + col4];
            if (n < N_NODES) {
                ushort4 u = *(const ushort4*)(sU + (size_t)n * 128 + col4);
                a[0] = bf2f(u.x); a[1] = bf2f(u.y); a[2] = bf2f(u.z); a[3] = bf2f(u.w);
            } else { a[0] = a[1] = a[2] = a[3] = 0.f; }
        }
    }
    for (int idx = t; idx < NB * 32; idx += 256) {       // agg part (always fp32 ws)
        int ni = idx >> 5, col4 = (idx & 31) * 4;
        int n = n0 + ni;
        float* a = &A2[ni * LDA2 + 128 + col4];
        if (n < N_NODES) {
            float4 u = *(const float4*)(agg_s + (size_t)n * 128 + col4);
            a[0] = u.x * 0.1f; a[1] = u.y * 0.1f; a[2] = u.z * 0.1f; a[3] = u.w * 0.1f;
        } else { a[0] = a[1] = a[2] = a[3] = 0.f; }
    }
    for (int idx = t; idx < NB * 96; idx += 256) {       // vcat = [v | agg_v/10]
        int ni = idx / 96, vc = idx % 96;
        int n = n0 + ni;
        float val = 0.f;
        if (n < N_NODES)
            val = (vc < 48) ? ldf(vP, n * 48 + vc, m)
                            : agg_v[(size_t)n * 48 + (vc - 48)] * 0.1f;
        Bs2[ni * 100 + vc] = val;
    }
    __syncthreads();
    // phase B: WhWu2 = Wh_u @ Wu_u ; sh_u -> A2 cols 256..287
    for (int idx = t; idx < HU * 16; idx += 256) {
        int vv = idx / 16, o = idx % 16;
        float acc = 0.f;
        for (int h = 0; h < HU; ++h)
            acc += WhS[vv * HU + h] * gates2[h * 16 + o];
        WhWu2[idx] = acc;
    }
    for (int idx = t; idx < NB * HU; idx += 256) {
        int ni = idx / HU, h = idx % HU;
        const float* vc = &Bs2[ni * 100];
        float vh0 = 0.f, vh1 = 0.f, vh2 = 0.f;
        for (int vv = 0; vv < HU; ++vv) {
            float w = WhS[vv * HU + h];
            vh0 += vc[vv * 3 + 0] * w; vh1 += vc[vv * 3 + 1] * w; vh2 += vc[vv * 3 + 2] * w;
        }
        A2[ni * LDA2 + 256 + h] = sqrtf(fmaxf(vh0 * vh0 + vh1 * vh1 + vh2 * vh2, 1e-8f));
    }
    __syncthreads();
    // phase C: Vu_u into registers (6 per thread, flat 32*48)
    float vureg[6];
    for (int r = 0; r < 6; ++r) {
        int idx = t + 256 * r;
        int ni = idx / 48, oc = idx % 48, o = oc / 3, c = oc % 3;
        const float* vc = &Bs2[ni * 100];
        float acc = 0.f;
        for (int vv = 0; vv < HU; ++vv)
            acc += vc[vv * 3 + c] * WhWu2[vv * 16 + o];
        vureg[r] = acc;
    }
    __syncthreads();

    // GEMM feats[32][128] = A2[32][288] @ Wf[288][128]; cols {tj + 16*jj}
    const int tj = t & 15, tn = t >> 4;
    const int nb = tn * 2;
    float acc[2][8];
    #pragma unroll
    for (int i = 0; i < 2; ++i)
        #pragma unroll
        for (int j = 0; j < 8; ++j) acc[i][j] = 0.f;

    for (int kk = 0; kk < KU; kk += 32) {
        if (m) {
            const float* WfF = (const float*)WfP;
            for (int idx = t; idx < 32 * 32; idx += 256) {
                int kt = idx >> 5, col4 = (idx & 31) * 4;
                float4 u = *(const float4*)(WfF + (size_t)(kk + kt) * 128 + col4);
                float* b = &Bs2[kt * 128 + col4];
                b[0] = u.x; b[1] = u.y; b[2] = u.z; b[3] = u.w;
            }
        } else {
            const unsigned short* WfU = (const unsigned short*)WfP;
            for (int idx = t; idx < 32 * 32; idx += 256) {
                int kt = idx >> 5, col4 = (idx & 31) * 4;
                ushort4 u = *(const ushort4*)(WfU + (size_t)(kk + kt) * 128 + col4);
                float* b = &Bs2[kt * 128 + col4];
                b[0] = bf2f(u.x); b[1] = bf2f(u.y); b[2] = bf2f(u.z); b[3] = bf2f(u.w);
            }
        }
        __syncthreads();
        for (int kt = 0; kt < 32; ++kt) {
            float a0 = A2[(nb + 0) * LDA2 + kk + kt];
            float a1 = A2[(nb + 1) * LDA2 + kk + kt];
            const float* brow = &Bs2[kt * 128 + tj];
            #pragma unroll
            for (int jj = 0; jj < 8; ++jj) {
                float b = brow[16 * jj];
                acc[0][jj] += a0 * b; acc[1][jj] += a1 * b;
            }
        }
        __syncthreads();
    }
    // bias + silu -> feats into A2 cols 128..255
    float breg[8];
    #pragma unroll
    for (int jj = 0; jj < 8; ++jj) breg[jj] = ldf(bfP, tj + 16 * jj, m);
    #pragma unroll
    for (int i = 0; i < 2; ++i) {
        float* aout = &A2[(nb + i) * LDA2 + 128];
        #pragma unroll
        for (int jj = 0; jj < 8; ++jj)
            aout[tj + 16 * jj] = silu_f(acc[i][jj] + breg[jj]);
    }
    __syncthreads();
    // stage Wg -> Bs2[0..2047]
    if (m) {
        const float* Wg = (const float*)WgP;
        for (int i = t; i < 2048; i += 256) Bs2[i] = Wg[i];
    } else {
        const unsigned short* Wg = (const unsigned short*)WgP;
        for (int i = t; i < 2048; i += 256) Bs2[i] = bf2f(Wg[i]);
    }
    __syncthreads();
    // gates
    for (int r = 0; r < 2; ++r) {
        int idx = t + 256 * r;
        int ni = idx / 16, o = idx % 16;
        const float* fe = &A2[ni * LDA2 + 128];
        float g = ldf(bgP, o, m);
        for (int j = 0; j < 128; ++j)
            g += fe[j] * Bs2[j * 16 + o];
        gates2[idx] = sigm_f(g);
    }
    __syncthreads();
    // v_res = v + gate*Vu  -> Bs2[ni*48+oc]
    for (int r = 0; r < 6; ++r) {
        int idx = t + 256 * r;
        int ni = idx / 48, oc = idx % 48, o = oc / 3;
        int n = n0 + ni;
        float vres = 0.f;
        if (n < N_NODES)
            vres = ldf(vP, n * 48 + oc, m) + vureg[r] * gates2[ni * 16 + o];
        Bs2[ni * 48 + oc] = vres;
    }
    __syncthreads();
    // per-node stats
    if (t < NB) {
        const float* arow = &A2[t * LDA2];
        float sum = 0.f, sumsq = 0.f;
        for (int j = 0; j < 128; ++j) {
            float xr = arow[j] + arow[128 + j];
            sum += xr; sumsq += xr * xr;
        }
        float mu = sum * (1.f / 128.f);
        float var = sumsq * (1.f / 128.f) - mu * mu;
        mu_s[t] = mu;
        rstd_s[t] = rsqrtf(fmaxf(var, 0.f) + 1e-5f);
        const float* vr = &Bs2[t * 48];
        float accv = 0.f;
        for (int o = 0; o < 16; ++o) {
            float mm = vr[o*3]*vr[o*3] + vr[o*3+1]*vr[o*3+1] + vr[o*3+2]*vr[o*3+2];
            accv += fmaxf(mm, 1e-8f);
        }
        vn_s[t] = sqrtf(accv * (1.f / 16.f) + 1e-5f) + 1e-5f;
    }
    __syncthreads();
    // outputs (dtype per mode)
    float* outF = (float*)outP;
    unsigned short* outU = (unsigned short*)outP;
    for (int idx = t; idx < NB * 128; idx += 256) {
        int ni = idx >> 7, j = idx & 127;
        int n = n0 + ni;
        if (n < N_NODES) {
            float xr = A2[ni * LDA2 + j] + A2[ni * LDA2 + 128 + j];
            float o = (xr - mu_s[ni]) * rstd_s[ni] * ldf(lngP, j, m) + ldf(lnbP, j, m);
            if (m) outF[(size_t)n * 128 + j] = o;
            else   outU[(size_t)n * 128 + j] = f2bf(o);
        }
    }
    for (int idx = t; idx < NB * 48; idx += 256) {
        int ni = idx / 48, oc = idx % 48;
        int n = n0 + ni;
        if (n < N_NODES) {
            float o = Bs2[ni * 48 + oc] / vn_s[ni];
            if (m) outF[(size_t)N_NODES * 128 + (size_t)n * 48 + oc] = o;
            else   outU[(size_t)N_NODES * 128 + (size_t)n * 48 + oc] = f2bf(o);
        }
    }
}

extern "C" void kernel_launch(void* const* d_in, const int* in_sizes, int n_in,
                              void* d_out, int out_size, void* d_ws, size_t ws_size,
                              hipStream_t stream) {
    const int* ei = (const int*)d_in[17];

    int* flag = (int*)d_ws;
    float* agg_s = (float*)((char*)d_ws + 64);
    float* agg_v = agg_s + (size_t)N_NODES * 128;
    hipMemsetAsync(d_ws, 0, 64 + (size_t)N_NODES * (128 + 48) * sizeof(float), stream);

    detect_kernel<<<1, 64, 0, stream>>>((const unsigned short*)d_in[0], flag);

    edge_kernel<<<E_EDGES / EB, 256, 0, stream>>>(
        d_in[0], d_in[1], d_in[2], d_in[3], d_in[4], d_in[5],
        d_in[6], d_in[7], d_in[8], ei, flag, agg_s, agg_v);
    node_kernel<<<(N_NODES + NB - 1) / NB, 256, 0, stream>>>(
        d_in[0], d_in[1], d_in[9], d_in[10], d_in[11], d_in[12],
        d_in[13], d_in[14], d_in[15], d_in[16], flag,
        agg_s, agg_v, d_out);
}